// Round 6
// baseline (790.574 us; speedup 1.0000x reference)
//
#include <hip/hip_runtime.h>
#include <hip/hip_bf16.h>
#include <math.h>

#define DD 128
#define BKT 64              // dst rows per bucket
#define NBMAX 1024
#define P_THR 1024
#define P_CH  16384         // edges per partition block

using bf16x8 = __attribute__((ext_vector_type(8))) short;
using f32x4  = __attribute__((ext_vector_type(4))) float;

struct alignas(16) bfq { __hip_bfloat162 q[4]; };

// ---------------- P1: bucket counts (LDS hist) + deg_src global histogram
__global__ __launch_bounds__(P_THR) void pcount_kernel(
        const int* __restrict__ src, const int* __restrict__ dst,
        unsigned int* __restrict__ deg_src, unsigned int* __restrict__ bucket_cnt,
        int E, int NB) {
    __shared__ unsigned int hist[NBMAX];
    int t = threadIdx.x;
    for (int b = t; b < NB; b += P_THR) hist[b] = 0;
    __syncthreads();
    int cbase = blockIdx.x * P_CH;
    for (int j = 0; j < P_CH; j += P_THR) {
        int i = cbase + j + t;
        if (i < E) {
            atomicAdd(&deg_src[src[i]], 1u);
            atomicAdd(&hist[dst[i] >> 6], 1u);   // LDS atomic
        }
    }
    __syncthreads();
    for (int b = t; b < NB; b += P_THR)
        if (hist[b]) atomicAdd(&bucket_cnt[b], hist[b]);
}

// ---------------- P2: exclusive scan of bucket counts (single wave)
__global__ void pscan_kernel(const unsigned int* __restrict__ cnt,
                             unsigned int* __restrict__ base_,
                             unsigned int* __restrict__ cur, int NB) {
    int lane = threadIdx.x;   // 64 threads
    unsigned int carry = 0;
    for (int b0 = 0; b0 < NB; b0 += 64) {
        int i = b0 + lane;
        unsigned int v = (i < NB) ? cnt[i] : 0u;
        unsigned int incl = v;
#pragma unroll
        for (int off = 1; off < 64; off <<= 1) {
            unsigned int u = __shfl_up(incl, off);
            if (lane >= off) incl += u;
        }
        unsigned int excl = incl - v + carry;
        if (i < NB) { base_[i] = excl; cur[i] = excl; }
        carry += __shfl(incl, 63);
    }
    if (lane == 0) base_[NB] = carry;
}

// ---------------- P3: scatter packed (dst,src) into bucket regions
__global__ __launch_bounds__(P_THR) void pscatter_kernel(
        const int* __restrict__ src, const int* __restrict__ dst,
        unsigned int* __restrict__ bucket_cur,
        unsigned long long* __restrict__ eparts, int E, int NB) {
    __shared__ unsigned int hist[NBMAX];
    __shared__ unsigned int sbase[NBMAX];
    int t = threadIdx.x;
    for (int b = t; b < NB; b += P_THR) hist[b] = 0;
    __syncthreads();
    int cbase = blockIdx.x * P_CH;
    for (int j = 0; j < P_CH; j += P_THR) {
        int i = cbase + j + t;
        if (i < E) atomicAdd(&hist[dst[i] >> 6], 1u);
    }
    __syncthreads();
    for (int b = t; b < NB; b += P_THR) {
        unsigned int hc = hist[b];
        sbase[b] = hc ? atomicAdd(&bucket_cur[b], hc) : 0u;
        hist[b] = 0;   // reuse as local cursor
    }
    __syncthreads();
    for (int j = 0; j < P_CH; j += P_THR) {
        int i = cbase + j + t;
        if (i < E) {
            int d = dst[i];
            int bin = d >> 6;
            unsigned int pos = sbase[bin] + atomicAdd(&hist[bin], 1u);
            eparts[pos] = ((unsigned long long)(unsigned int)d << 32) |
                          (unsigned int)src[i];
        }
    }
}

// ---------------- h (f32) -> hb (bf16), pre-scaled by rsqrt(max(deg_src,1))
__global__ __launch_bounds__(256) void conv_kernel(
        const float* __restrict__ h, const unsigned int* __restrict__ deg_src,
        __hip_bfloat16* __restrict__ hb, int num_src) {
    int idx = blockIdx.x * 256 + threadIdx.x;      // one thread per 8 elems
    int total = num_src * (DD / 8);
    if (idx >= total) return;
    int row = idx >> 4;
    int c0  = (idx & 15) * 8;
    float nrm = rsqrtf(fmaxf((float)deg_src[row], 1.0f));
    const float4* p = reinterpret_cast<const float4*>(h + (size_t)row * DD + c0);
    float4 a = p[0], b = p[1];
    bfq o;
    o.q[0] = __float22bfloat162_rn(make_float2(a.x * nrm, a.y * nrm));
    o.q[1] = __float22bfloat162_rn(make_float2(a.z * nrm, a.w * nrm));
    o.q[2] = __float22bfloat162_rn(make_float2(b.x * nrm, b.y * nrm));
    o.q[3] = __float22bfloat162_rn(make_float2(b.z * nrm, b.w * nrm));
    *reinterpret_cast<bfq*>(hb + (size_t)row * DD + c0) = o;
}

// -------------------------------------------------- W -> Wt (transposed bf16)
__global__ void wt_kernel(const float* __restrict__ Wm,
                          __hip_bfloat16* __restrict__ Wt) {
    int idx = blockIdx.x * blockDim.x + threadIdx.x;  // idx = c*128 + k
    if (idx < DD * DD) {
        int c = idx >> 7, k = idx & 127;
        Wt[idx] = __float2bfloat16(Wm[k * DD + c]);
    }
}

// ---------------- fused bucket aggregate: LDS f32 accum, no global atomics
#define GW 4   // waves per block
__global__ __launch_bounds__(256) void bgather_kernel(
        const __hip_bfloat16* __restrict__ hb,
        const unsigned long long* __restrict__ eparts,
        const unsigned int* __restrict__ bucket_base,
        __hip_bfloat16* __restrict__ aggb, int num_dst) {
    __shared__ float sagg[BKT * DD];     // 32 KB
    __shared__ unsigned int sdeg[BKT];
    int t = threadIdx.x, wid = t >> 6, lane = t & 63;
    int b = blockIdx.x;

    for (int i = t * 4; i < BKT * DD; i += 256 * 4)
        *reinterpret_cast<float4*>(&sagg[i]) = make_float4(0.f, 0.f, 0.f, 0.f);
    if (t < BKT) sdeg[t] = 0;
    __syncthreads();

    unsigned int e0 = bucket_base[b], e1 = bucket_base[b + 1];
    const __hip_bfloat162* hb2 = reinterpret_cast<const __hip_bfloat162*>(hb);

    unsigned int i = e0 + wid;
    for (; i + 3 * GW < e1; i += 4 * GW) {
        unsigned long long ea = eparts[i];
        unsigned long long eb = eparts[i + GW];
        unsigned long long ec = eparts[i + 2 * GW];
        unsigned long long ed = eparts[i + 3 * GW];
        int da = ((int)(ea >> 32)) & (BKT - 1); int sa = (int)(ea & 0xffffffffULL);
        int db = ((int)(eb >> 32)) & (BKT - 1); int sb = (int)(eb & 0xffffffffULL);
        int dc = ((int)(ec >> 32)) & (BKT - 1); int sc = (int)(ec & 0xffffffffULL);
        int dd = ((int)(ed >> 32)) & (BKT - 1); int sd = (int)(ed & 0xffffffffULL);
        float2 va = __bfloat1622float2(hb2[(size_t)sa * 64 + lane]);
        float2 vb = __bfloat1622float2(hb2[(size_t)sb * 64 + lane]);
        float2 vc = __bfloat1622float2(hb2[(size_t)sc * 64 + lane]);
        float2 vd = __bfloat1622float2(hb2[(size_t)sd * 64 + lane]);
        if (lane == 0) {
            atomicAdd(&sdeg[da], 1u); atomicAdd(&sdeg[db], 1u);
            atomicAdd(&sdeg[dc], 1u); atomicAdd(&sdeg[dd], 1u);
        }
        atomicAdd(&sagg[da * DD + lane * 2],     va.x);
        atomicAdd(&sagg[da * DD + lane * 2 + 1], va.y);
        atomicAdd(&sagg[db * DD + lane * 2],     vb.x);
        atomicAdd(&sagg[db * DD + lane * 2 + 1], vb.y);
        atomicAdd(&sagg[dc * DD + lane * 2],     vc.x);
        atomicAdd(&sagg[dc * DD + lane * 2 + 1], vc.y);
        atomicAdd(&sagg[dd * DD + lane * 2],     vd.x);
        atomicAdd(&sagg[dd * DD + lane * 2 + 1], vd.y);
    }
    for (; i < e1; i += GW) {
        unsigned long long ea = eparts[i];
        int da = ((int)(ea >> 32)) & (BKT - 1); int sa = (int)(ea & 0xffffffffULL);
        float2 va = __bfloat1622float2(hb2[(size_t)sa * 64 + lane]);
        if (lane == 0) atomicAdd(&sdeg[da], 1u);
        atomicAdd(&sagg[da * DD + lane * 2],     va.x);
        atomicAdd(&sagg[da * DD + lane * 2 + 1], va.y);
    }
    __syncthreads();

    for (int r = wid; r < BKT; r += GW) {
        int row = b * BKT + r;
        if (row >= num_dst) break;
        float sc = rsqrtf(fmaxf((float)sdeg[r], 1.0f));
        float2 v = make_float2(sagg[r * DD + lane * 2] * sc,
                               sagg[r * DD + lane * 2 + 1] * sc);
        *reinterpret_cast<__hip_bfloat162*>(aggb + (size_t)row * DD + lane * 2) =
            __float22bfloat162_rn(v);
    }
}

// ---------------------- MFMA GEMM (aggb @ W + b) + attention epilogue
__global__ __launch_bounds__(256) void out_mfma_kernel(
        const __hip_bfloat16* __restrict__ aggb,
        const __hip_bfloat16* __restrict__ Wt,   // [c][k] bf16
        const float* __restrict__ bias, const float* __restrict__ w_attn,
        float* __restrict__ out, float* __restrict__ alpha_out, int num_dst) {
    int wave = threadIdx.x >> 6;
    int lane = threadIdx.x & 63;
    int row0 = blockIdx.x * 64 + wave * 16;
    if (row0 >= num_dst) return;

    int col = lane & 15;
    int hi  = lane >> 4;

    int arow = row0 + col;
    if (arow >= num_dst) arow = num_dst - 1;

    f32x4 acc[8];
#pragma unroll
    for (int ct = 0; ct < 8; ++ct) acc[ct] = (f32x4)0.f;

    const bf16x8* A = reinterpret_cast<const bf16x8*>(aggb + (size_t)arow * DD);
#pragma unroll
    for (int kg = 0; kg < 4; ++kg) {
        bf16x8 a = A[kg * 4 + hi];
#pragma unroll
        for (int ct = 0; ct < 8; ++ct) {
            const bf16x8* B =
                reinterpret_cast<const bf16x8*>(Wt + (size_t)(ct * 16 + col) * DD);
            bf16x8 b = B[kg * 4 + hi];
            acc[ct] = __builtin_amdgcn_mfma_f32_16x16x32_bf16(a, b, acc[ct], 0, 0, 0);
        }
    }

    float wv[8], bv[8];
#pragma unroll
    for (int ct = 0; ct < 8; ++ct) {
        wv[ct] = w_attn[ct * 16 + col];
        bv[ct] = bias[ct * 16 + col];
    }

#pragma unroll
    for (int r = 0; r < 4; ++r) {
        int row = row0 + hi * 4 + r;
        float v[8];
        float s = 0.f;
#pragma unroll
        for (int ct = 0; ct < 8; ++ct) {
            v[ct] = acc[ct][r] + bv[ct];
            s = fmaf(v[ct], wv[ct], s);
        }
        s += __shfl_xor(s, 1);
        s += __shfl_xor(s, 2);
        s += __shfl_xor(s, 4);
        s += __shfl_xor(s, 8);
        float alpha = 1.0f / (1.0f + expf(-s));
        if (row < num_dst) {
#pragma unroll
            for (int ct = 0; ct < 8; ++ct)
                out[(size_t)row * DD + ct * 16 + col] = v[ct] * alpha;
            if (col == 0) alpha_out[row] = alpha;
        }
    }
}

// ----------------------------------------------------------------- launch
extern "C" void kernel_launch(void* const* d_in, const int* in_sizes, int n_in,
                              void* d_out, int out_size, void* d_ws, size_t ws_size,
                              hipStream_t stream) {
    const float* h      = (const float*)d_in[0];
    const int*   src    = (const int*)d_in[1];
    const int*   dst    = (const int*)d_in[2];
    const float* Wm     = (const float*)d_in[3];
    const float* bias   = (const float*)d_in[4];
    const float* w_attn = (const float*)d_in[5];

    int num_src = in_sizes[0] / DD;
    int E       = in_sizes[1];
    int num_dst = out_size / (DD + 1);
    int NB      = (num_dst + BKT - 1) / BKT;    // 782 (<= NBMAX)

    float* out       = (float*)d_out;
    float* alpha_out = out + (size_t)num_dst * DD;

    char* p = (char*)d_ws;
    auto take = [&p](size_t bytes) {
        char* q = p;
        p += (bytes + 255) & ~(size_t)255;
        return q;
    };
    unsigned int* deg_src    = (unsigned int*)take((size_t)num_src * 4);
    unsigned int* bucket_cnt = (unsigned int*)take((size_t)NB * 4);
    size_t zero_bytes = (size_t)((char*)bucket_cnt - (char*)deg_src) + (size_t)NB * 4;
    unsigned int* bucket_base = (unsigned int*)take((size_t)(NB + 8) * 4);
    unsigned int* bucket_cur  = (unsigned int*)take((size_t)NB * 4);
    unsigned long long* eparts = (unsigned long long*)take((size_t)E * 8);
    __hip_bfloat16* aggb = (__hip_bfloat16*)take((size_t)num_dst * DD * 2);
    __hip_bfloat16* Wt   = (__hip_bfloat16*)take((size_t)DD * DD * 2);
    __hip_bfloat16* hb   = (__hip_bfloat16*)take((size_t)num_src * DD * 2);

    hipMemsetAsync(deg_src, 0, zero_bytes, stream);

    int pgrid = (E + P_CH - 1) / P_CH;
    pcount_kernel<<<pgrid, P_THR, 0, stream>>>(src, dst, deg_src, bucket_cnt, E, NB);
    pscan_kernel<<<1, 64, 0, stream>>>(bucket_cnt, bucket_base, bucket_cur, NB);
    pscatter_kernel<<<pgrid, P_THR, 0, stream>>>(src, dst, bucket_cur, eparts, E, NB);

    int thr = 256;
    int totalc = num_src * (DD / 8);
    conv_kernel<<<(totalc + thr - 1) / thr, thr, 0, stream>>>(h, deg_src, hb, num_src);
    wt_kernel<<<(DD * DD + thr - 1) / thr, thr, 0, stream>>>(Wm, Wt);

    bgather_kernel<<<NB, thr, 0, stream>>>(hb, eparts, bucket_base, aggb, num_dst);

    int grid_c = (num_dst + 63) / 64;
    out_mfma_kernel<<<grid_c, thr, 0, stream>>>(aggb, Wt, bias, w_attn,
                                                out, alpha_out, num_dst);
}

// Round 7
// 146.604 us; speedup vs baseline: 5.3926x; 5.3926x over previous
//
#include <hip/hip_runtime.h>
#include <hip/hip_bf16.h>
#include <math.h>

#define DD 128
#define MAXDEG 64
#define HBINS 16384          // bins per histogram pass (64KB LDS)
#define HBLK  32             // edge-chunks per pass
#define HTHR  1024

using bf16x8 = __attribute__((ext_vector_type(8))) short;
using f32x4  = __attribute__((ext_vector_type(4))) float;

struct alignas(16) bfq { __hip_bfloat162 q[4]; };

// ---------------- deg_src multipass LDS histogram (no global atomics)
// grid.x = NPASS*HBLK; pass = blk/HBLK selects bin range, blk%HBLK selects edges
__global__ __launch_bounds__(HTHR) void hist_part_kernel(
        const int* __restrict__ src, unsigned int* __restrict__ parts, int E) {
    __shared__ unsigned int hist[HBINS];
    int t = threadIdx.x;
    int pass = blockIdx.x / HBLK;
    int blk  = blockIdx.x % HBLK;
    int lo   = pass * HBINS;
#pragma unroll
    for (int i = t; i < HBINS; i += HTHR) hist[i] = 0;
    __syncthreads();
    int chunk = (E + HBLK - 1) / HBLK;
    int c0 = blk * chunk;
    int c1 = c0 + chunk; if (c1 > E) c1 = E;
    for (int i = c0 + t; i < c1; i += HTHR) {
        unsigned int u = (unsigned int)(src[i] - lo);
        if (u < HBINS) atomicAdd(&hist[u], 1u);    // LDS atomic
    }
    __syncthreads();
    unsigned int* dstp = parts + ((size_t)blockIdx.x << 14);
    for (int i = t; i < HBINS; i += HTHR) dstp[i] = hist[i];
}

__global__ void hist_merge_kernel(const unsigned int* __restrict__ parts,
                                  unsigned int* __restrict__ deg_src, int num_src) {
    int g = blockIdx.x * blockDim.x + threadIdx.x;
    if (g >= num_src) return;
    int pass = g >> 14;
    int r = g & (HBINS - 1);
    const unsigned int* p = parts + ((size_t)(pass * HBLK) << 14) + r;
    unsigned int s = 0;
#pragma unroll
    for (int b = 0; b < HBLK; ++b) s += p[(size_t)b << 14];
    deg_src[g] = s;
}

// ---------------- CSR fill: cursor atomic + scattered store only
__global__ void fillc_kernel(const int* __restrict__ src, const int* __restrict__ dst,
                             unsigned int* __restrict__ cursor,
                             int* __restrict__ csr, int E) {
    int i = blockIdx.x * blockDim.x + threadIdx.x;
    if (i < E) {
        int s = src[i];
        int d = dst[i];
        unsigned int pos = atomicAdd(&cursor[d], 1u);
        if (pos < MAXDEG) csr[(size_t)d * MAXDEG + pos] = s;
    }
}

// ---------------- fallback: fused atomic version (R5 fill2)
__global__ void fill2_kernel(const int* __restrict__ src, const int* __restrict__ dst,
                             unsigned int* __restrict__ deg_src,
                             unsigned int* __restrict__ cursor,
                             int* __restrict__ csr, int E) {
    int i = blockIdx.x * blockDim.x + threadIdx.x;
    if (i < E) {
        int s = src[i];
        int d = dst[i];
        atomicAdd(&deg_src[s], 1u);
        unsigned int pos = atomicAdd(&cursor[d], 1u);
        if (pos < MAXDEG) csr[(size_t)d * MAXDEG + pos] = s;
    }
}

// ---------------- h (f32) -> hb (bf16), pre-scaled by rsqrt(max(deg_src,1))
__global__ __launch_bounds__(256) void conv_kernel(
        const float* __restrict__ h, const unsigned int* __restrict__ deg_src,
        __hip_bfloat16* __restrict__ hb, int num_src) {
    int idx = blockIdx.x * 256 + threadIdx.x;      // one thread per 8 elems
    int total = num_src * (DD / 8);
    if (idx >= total) return;
    int row = idx >> 4;
    int c0  = (idx & 15) * 8;
    float nrm = rsqrtf(fmaxf((float)deg_src[row], 1.0f));
    const float4* p = reinterpret_cast<const float4*>(h + (size_t)row * DD + c0);
    float4 a = p[0], b = p[1];
    bfq o;
    o.q[0] = __float22bfloat162_rn(make_float2(a.x * nrm, a.y * nrm));
    o.q[1] = __float22bfloat162_rn(make_float2(a.z * nrm, a.w * nrm));
    o.q[2] = __float22bfloat162_rn(make_float2(b.x * nrm, b.y * nrm));
    o.q[3] = __float22bfloat162_rn(make_float2(b.z * nrm, b.w * nrm));
    *reinterpret_cast<bfq*>(hb + (size_t)row * DD + c0) = o;
}

// -------------------------------------------------- W -> Wt (transposed bf16)
__global__ void wt_kernel(const float* __restrict__ Wm,
                          __hip_bfloat16* __restrict__ Wt) {
    int idx = blockIdx.x * blockDim.x + threadIdx.x;  // idx = c*128 + k
    if (idx < DD * DD) {
        int c = idx >> 7, k = idx & 127;
        Wt[idx] = __float2bfloat16(Wm[k * DD + c]);
    }
}

// ---------------- gather-aggregate; FOLDED=1 reads pre-scaled bf16 hb
template <int FOLDED>
__global__ __launch_bounds__(256) void gather_kernel(
        const float* __restrict__ h, const __hip_bfloat16* __restrict__ hb,
        const int* __restrict__ csr, const unsigned int* __restrict__ cursor,
        const unsigned int* __restrict__ deg_src,
        __hip_bfloat16* __restrict__ aggb, int num_dst) {
    int wave = threadIdx.x >> 6;
    int lane = threadIdx.x & 63;
    int row = blockIdx.x * 4 + wave;
    if (row >= num_dst) return;
    unsigned int degu = cursor[row];
    int deg = (int)degu; if (deg > MAXDEG) deg = MAXDEG;
    const int* crow = csr + (size_t)row * MAXDEG;
    int c = lane * 2;
    float ax = 0.f, ay = 0.f;
    int i = 0;
    if (FOLDED) {
        for (; i + 8 <= deg; i += 8) {
            int4 s0 = *reinterpret_cast<const int4*>(crow + i);
            int4 s1 = *reinterpret_cast<const int4*>(crow + i + 4);
            float2 v0 = __bfloat1622float2(*reinterpret_cast<const __hip_bfloat162*>(hb + (size_t)s0.x * DD + c));
            float2 v1 = __bfloat1622float2(*reinterpret_cast<const __hip_bfloat162*>(hb + (size_t)s0.y * DD + c));
            float2 v2 = __bfloat1622float2(*reinterpret_cast<const __hip_bfloat162*>(hb + (size_t)s0.z * DD + c));
            float2 v3 = __bfloat1622float2(*reinterpret_cast<const __hip_bfloat162*>(hb + (size_t)s0.w * DD + c));
            float2 v4 = __bfloat1622float2(*reinterpret_cast<const __hip_bfloat162*>(hb + (size_t)s1.x * DD + c));
            float2 v5 = __bfloat1622float2(*reinterpret_cast<const __hip_bfloat162*>(hb + (size_t)s1.y * DD + c));
            float2 v6 = __bfloat1622float2(*reinterpret_cast<const __hip_bfloat162*>(hb + (size_t)s1.z * DD + c));
            float2 v7 = __bfloat1622float2(*reinterpret_cast<const __hip_bfloat162*>(hb + (size_t)s1.w * DD + c));
            ax += v0.x + v1.x + v2.x + v3.x + v4.x + v5.x + v6.x + v7.x;
            ay += v0.y + v1.y + v2.y + v3.y + v4.y + v5.y + v6.y + v7.y;
        }
        for (; i < deg; ++i) {
            int s = crow[i];
            float2 v = __bfloat1622float2(*reinterpret_cast<const __hip_bfloat162*>(hb + (size_t)s * DD + c));
            ax += v.x; ay += v.y;
        }
    } else {
        for (; i + 4 <= deg; i += 4) {
            int4 s0 = *reinterpret_cast<const int4*>(crow + i);
            float n0 = rsqrtf(fmaxf((float)deg_src[s0.x], 1.0f));
            float n1 = rsqrtf(fmaxf((float)deg_src[s0.y], 1.0f));
            float n2 = rsqrtf(fmaxf((float)deg_src[s0.z], 1.0f));
            float n3 = rsqrtf(fmaxf((float)deg_src[s0.w], 1.0f));
            float2 v0 = *reinterpret_cast<const float2*>(h + (size_t)s0.x * DD + c);
            float2 v1 = *reinterpret_cast<const float2*>(h + (size_t)s0.y * DD + c);
            float2 v2 = *reinterpret_cast<const float2*>(h + (size_t)s0.z * DD + c);
            float2 v3 = *reinterpret_cast<const float2*>(h + (size_t)s0.w * DD + c);
            ax = fmaf(v0.x, n0, ax); ay = fmaf(v0.y, n0, ay);
            ax = fmaf(v1.x, n1, ax); ay = fmaf(v1.y, n1, ay);
            ax = fmaf(v2.x, n2, ax); ay = fmaf(v2.y, n2, ay);
            ax = fmaf(v3.x, n3, ax); ay = fmaf(v3.y, n3, ay);
        }
        for (; i < deg; ++i) {
            int s = crow[i];
            float nn = rsqrtf(fmaxf((float)deg_src[s], 1.0f));
            float2 v = *reinterpret_cast<const float2*>(h + (size_t)s * DD + c);
            ax = fmaf(v.x, nn, ax); ay = fmaf(v.y, nn, ay);
        }
    }
    float scd = rsqrtf(fmaxf((float)degu, 1.0f));
    __hip_bfloat162 o;
    o.x = __float2bfloat16(ax * scd);
    o.y = __float2bfloat16(ay * scd);
    *reinterpret_cast<__hip_bfloat162*>(aggb + (size_t)row * DD + c) = o;
}

// ---------------------- MFMA GEMM (aggb @ W + b) + attention epilogue
__global__ __launch_bounds__(256) void out_mfma_kernel(
        const __hip_bfloat16* __restrict__ aggb,
        const __hip_bfloat16* __restrict__ Wt,   // [c][k] bf16
        const float* __restrict__ bias, const float* __restrict__ w_attn,
        float* __restrict__ out, float* __restrict__ alpha_out, int num_dst) {
    int wave = threadIdx.x >> 6;
    int lane = threadIdx.x & 63;
    int row0 = blockIdx.x * 64 + wave * 16;
    if (row0 >= num_dst) return;

    int col = lane & 15;
    int hi  = lane >> 4;

    int arow = row0 + col;
    if (arow >= num_dst) arow = num_dst - 1;

    f32x4 acc[8];
#pragma unroll
    for (int ct = 0; ct < 8; ++ct) acc[ct] = (f32x4)0.f;

    const bf16x8* A = reinterpret_cast<const bf16x8*>(aggb + (size_t)arow * DD);
#pragma unroll
    for (int kg = 0; kg < 4; ++kg) {
        bf16x8 a = A[kg * 4 + hi];
#pragma unroll
        for (int ct = 0; ct < 8; ++ct) {
            const bf16x8* B =
                reinterpret_cast<const bf16x8*>(Wt + (size_t)(ct * 16 + col) * DD);
            bf16x8 b = B[kg * 4 + hi];
            acc[ct] = __builtin_amdgcn_mfma_f32_16x16x32_bf16(a, b, acc[ct], 0, 0, 0);
        }
    }

    float wv[8], bv[8];
#pragma unroll
    for (int ct = 0; ct < 8; ++ct) {
        wv[ct] = w_attn[ct * 16 + col];
        bv[ct] = bias[ct * 16 + col];
    }

#pragma unroll
    for (int r = 0; r < 4; ++r) {
        int row = row0 + hi * 4 + r;
        float v[8];
        float s = 0.f;
#pragma unroll
        for (int ct = 0; ct < 8; ++ct) {
            v[ct] = acc[ct][r] + bv[ct];
            s = fmaf(v[ct], wv[ct], s);
        }
        s += __shfl_xor(s, 1);
        s += __shfl_xor(s, 2);
        s += __shfl_xor(s, 4);
        s += __shfl_xor(s, 8);
        float alpha = 1.0f / (1.0f + expf(-s));
        if (row < num_dst) {
#pragma unroll
            for (int ct = 0; ct < 8; ++ct)
                out[(size_t)row * DD + ct * 16 + col] = v[ct] * alpha;
            if (col == 0) alpha_out[row] = alpha;
        }
    }
}

// ----------------------------------------------------------------- launch
extern "C" void kernel_launch(void* const* d_in, const int* in_sizes, int n_in,
                              void* d_out, int out_size, void* d_ws, size_t ws_size,
                              hipStream_t stream) {
    const float* h      = (const float*)d_in[0];
    const int*   src    = (const int*)d_in[1];
    const int*   dst    = (const int*)d_in[2];
    const float* Wm     = (const float*)d_in[3];
    const float* bias   = (const float*)d_in[4];
    const float* w_attn = (const float*)d_in[5];

    int num_src = in_sizes[0] / DD;
    int E       = in_sizes[1];
    int num_dst = out_size / (DD + 1);
    int NPASS   = (num_src + HBINS - 1) / HBINS;   // 7 for 100K

    float* out       = (float*)d_out;
    float* alpha_out = out + (size_t)num_dst * DD;

    char* p = (char*)d_ws;
    auto take = [&p](size_t bytes) {
        char* q = p;
        p += (bytes + 255) & ~(size_t)255;
        return q;
    };
    unsigned int* deg_src = (unsigned int*)take((size_t)num_src * 4);
    unsigned int* cursor  = (unsigned int*)take((size_t)num_dst * 4);
    int*            csr   = (int*)take((size_t)num_dst * MAXDEG * 4);
    __hip_bfloat16* aggb  = (__hip_bfloat16*)take((size_t)num_dst * DD * 2);
    __hip_bfloat16* Wt    = (__hip_bfloat16*)take((size_t)DD * DD * 2);
    __hip_bfloat16* hb    = (__hip_bfloat16*)take((size_t)num_src * DD * 2);
    size_t base_need = (size_t)(p - (char*)d_ws);
    unsigned int* parts   = (unsigned int*)take(((size_t)NPASS * HBLK) << 16);
    size_t full_need = (size_t)(p - (char*)d_ws);
    bool folded  = ws_size >= base_need;   // hb path
    bool use_mp  = ws_size >= full_need;   // multipass-hist path

    int thr = 256;
    if (use_mp) {
        // cursor zero only; deg_src written wholesale by merge
        hipMemsetAsync(cursor, 0, (size_t)num_dst * 4, stream);
        hist_part_kernel<<<NPASS * HBLK, HTHR, 0, stream>>>(src, parts, E);
        hist_merge_kernel<<<(num_src + thr - 1) / thr, thr, 0, stream>>>(
            parts, deg_src, num_src);
        fillc_kernel<<<(E + thr - 1) / thr, thr, 0, stream>>>(src, dst, cursor,
                                                              csr, E);
    } else {
        hipMemsetAsync(deg_src, 0, (size_t)num_src * 4, stream);
        hipMemsetAsync(cursor, 0, (size_t)num_dst * 4, stream);
        fill2_kernel<<<(E + thr - 1) / thr, thr, 0, stream>>>(src, dst, deg_src,
                                                              cursor, csr, E);
    }

    if (folded) {
        int totalc = num_src * (DD / 8);
        conv_kernel<<<(totalc + thr - 1) / thr, thr, 0, stream>>>(h, deg_src, hb,
                                                                  num_src);
    }
    wt_kernel<<<(DD * DD + thr - 1) / thr, thr, 0, stream>>>(Wm, Wt);

    int grid_g = (num_dst + 3) / 4;
    if (folded) {
        gather_kernel<1><<<grid_g, thr, 0, stream>>>(h, hb, csr, cursor, deg_src,
                                                     aggb, num_dst);
    } else {
        gather_kernel<0><<<grid_g, thr, 0, stream>>>(h, hb, csr, cursor, deg_src,
                                                     aggb, num_dst);
    }

    int grid_c = (num_dst + 63) / 64;
    out_mfma_kernel<<<grid_c, thr, 0, stream>>>(aggb, Wt, bias, w_attn,
                                                out, alpha_out, num_dst);
}

// Round 8
// 122.068 us; speedup vs baseline: 6.4765x; 1.2010x over previous
//
#include <hip/hip_runtime.h>
#include <hip/hip_bf16.h>
#include <math.h>

#define DD 128
#define MAXDEG 64
#define BKT 64               // dst rows per bucket
#define NB_MAX 1024
#define P_CH 8192            // edges per partition block
#define HBINS 16384          // bins per deg_src histogram pass (64KB LDS)
#define HBLK  32
#define HTHR  1024

using bf16x8 = __attribute__((ext_vector_type(8))) short;
using f32x4  = __attribute__((ext_vector_type(4))) float;

struct alignas(16) bfq { __hip_bfloat162 q[4]; };

// ---------------- deg_src multipass LDS histogram (no global atomics)
__global__ __launch_bounds__(HTHR) void hist_part_kernel(
        const int* __restrict__ src, unsigned int* __restrict__ parts, int E) {
    __shared__ unsigned int hist[HBINS];
    int t = threadIdx.x;
    int pass = blockIdx.x / HBLK;
    int blk  = blockIdx.x % HBLK;
    int lo   = pass * HBINS;
    for (int i = t; i < HBINS; i += HTHR) hist[i] = 0;
    __syncthreads();
    int chunk = (E + HBLK - 1) / HBLK;
    int c0 = blk * chunk;
    int c1 = c0 + chunk; if (c1 > E) c1 = E;
    for (int i = c0 + t; i < c1; i += HTHR) {
        unsigned int u = (unsigned int)(src[i] - lo);
        if (u < HBINS) atomicAdd(&hist[u], 1u);    // LDS int atomic
    }
    __syncthreads();
    unsigned int* dstp = parts + ((size_t)blockIdx.x << 14);
    for (int i = t; i < HBINS; i += HTHR) dstp[i] = hist[i];
}

__global__ void hist_merge_kernel(const unsigned int* __restrict__ parts,
                                  unsigned int* __restrict__ deg_src, int num_src) {
    int g = blockIdx.x * blockDim.x + threadIdx.x;
    if (g >= num_src) return;
    int pass = g >> 14;
    int r = g & (HBINS - 1);
    const unsigned int* p = parts + ((size_t)(pass * HBLK) << 14) + r;
    unsigned int s = 0;
#pragma unroll
    for (int b = 0; b < HBLK; ++b) s += p[(size_t)b << 14];
    deg_src[g] = s;
}

// ---------------- bucket counts (LDS hist, few global atomics)
__global__ __launch_bounds__(1024) void pcount_kernel(
        const int* __restrict__ dst, unsigned int* __restrict__ bucket_cnt,
        int E, int NB) {
    __shared__ unsigned int lhist[NB_MAX];
    int t = threadIdx.x;
    for (int b = t; b < NB; b += 1024) lhist[b] = 0;
    __syncthreads();
    int c0 = blockIdx.x * P_CH;
    int c1 = c0 + P_CH; if (c1 > E) c1 = E;
    for (int i = c0 + t; i < c1; i += 1024)
        atomicAdd(&lhist[dst[i] >> 6], 1u);
    __syncthreads();
    for (int b = t; b < NB; b += 1024)
        if (lhist[b]) atomicAdd(&bucket_cnt[b], lhist[b]);
}

// ---------------- exclusive scan of bucket counts (single wave)
__global__ void pscan_kernel(const unsigned int* __restrict__ cnt,
                             unsigned int* __restrict__ base_,
                             unsigned int* __restrict__ cur, int NB) {
    int lane = threadIdx.x;   // 64 threads
    unsigned int carry = 0;
    for (int b0 = 0; b0 < NB; b0 += 64) {
        int i = b0 + lane;
        unsigned int v = (i < NB) ? cnt[i] : 0u;
        unsigned int incl = v;
#pragma unroll
        for (int off = 1; off < 64; off <<= 1) {
            unsigned int u = __shfl_up(incl, off);
            if (lane >= off) incl += u;
        }
        unsigned int excl = incl - v + carry;
        if (i < NB) { base_[i] = excl; cur[i] = excl; }
        carry += __shfl(incl, 63);
    }
    if (lane == 0) base_[NB] = carry;
}

// ---------------- staged binning scatter: dense writes, 1 LDS atomic/edge ×2
__global__ __launch_bounds__(1024) void pscatter_kernel(
        const int* __restrict__ src, const int* __restrict__ dst,
        unsigned int* __restrict__ bucket_cur,
        unsigned int* __restrict__ eparts, int E, int NB) {
    __shared__ unsigned short stage_d[P_CH];   // 16KB
    __shared__ unsigned int   stage_s[P_CH];   // 32KB
    __shared__ unsigned int lhist[NB_MAX];     // counts -> cursors
    __shared__ unsigned int lbase[NB_MAX];     // scan buffer / local base
    __shared__ unsigned int gbase[NB_MAX];     // global run base
    int t = threadIdx.x;
    for (int b = t; b < NB_MAX; b += 1024) lhist[b] = 0;
    __syncthreads();
    int c0 = blockIdx.x * P_CH;
    int cnt = E - c0; if (cnt > P_CH) cnt = P_CH;

    int dreg[8], sreg[8];
#pragma unroll
    for (int k = 0; k < 8; ++k) {
        int j = t + k * 1024;
        if (j < cnt) {
            dreg[k] = dst[c0 + j];
            sreg[k] = src[c0 + j];
            atomicAdd(&lhist[dreg[k] >> 6], 1u);
        }
    }
    __syncthreads();
    // Hillis-Steele inclusive scan over 1024 slots -> exclusive lbase
    unsigned int v = lhist[t];
    lbase[t] = v;
    __syncthreads();
    for (int off = 1; off < 1024; off <<= 1) {
        unsigned int u = (t >= off) ? lbase[t - off] : 0u;
        __syncthreads();
        lbase[t] += u;
        __syncthreads();
    }
    unsigned int incl = lbase[t];
    __syncthreads();
    lbase[t] = incl - v;          // exclusive
    if (t < NB) {
        unsigned int c = lhist[t];
        gbase[t] = c ? atomicAdd(&bucket_cur[t], c) : 0u;
        lhist[t] = 0u;            // reuse as local cursor
    }
    __syncthreads();
    // place into LDS in bucket-sorted order
#pragma unroll
    for (int k = 0; k < 8; ++k) {
        int j = t + k * 1024;
        if (j < cnt) {
            int bin = dreg[k] >> 6;
            unsigned int pos = lbase[bin] + atomicAdd(&lhist[bin], 1u);
            stage_d[pos] = (unsigned short)dreg[k];
            stage_s[pos] = (unsigned int)sreg[k];
        }
    }
    __syncthreads();
    // dense run writes
    for (int idx = t; idx < cnt; idx += 1024) {
        unsigned int d = stage_d[idx];
        unsigned int bin = d >> 6;
        unsigned int pos = gbase[bin] + ((unsigned int)idx - lbase[bin]);
        eparts[pos] = ((d & 63u) << 24) | stage_s[idx];
    }
}

// ---------------- h (f32) -> hb (bf16), pre-scaled by rsqrt(max(deg_src,1))
__global__ __launch_bounds__(256) void conv_kernel(
        const float* __restrict__ h, const unsigned int* __restrict__ deg_src,
        __hip_bfloat16* __restrict__ hb, int num_src) {
    int idx = blockIdx.x * 256 + threadIdx.x;
    int total = num_src * (DD / 8);
    if (idx >= total) return;
    int row = idx >> 4;
    int c0  = (idx & 15) * 8;
    float nrm = rsqrtf(fmaxf((float)deg_src[row], 1.0f));
    const float4* p = reinterpret_cast<const float4*>(h + (size_t)row * DD + c0);
    float4 a = p[0], b = p[1];
    bfq o;
    o.q[0] = __float22bfloat162_rn(make_float2(a.x * nrm, a.y * nrm));
    o.q[1] = __float22bfloat162_rn(make_float2(a.z * nrm, a.w * nrm));
    o.q[2] = __float22bfloat162_rn(make_float2(b.x * nrm, b.y * nrm));
    o.q[3] = __float22bfloat162_rn(make_float2(b.z * nrm, b.w * nrm));
    *reinterpret_cast<bfq*>(hb + (size_t)row * DD + c0) = o;
}

// -------------------------------------------------- W -> Wt (transposed bf16)
__global__ void wt_kernel(const float* __restrict__ Wm,
                          __hip_bfloat16* __restrict__ Wt) {
    int idx = blockIdx.x * blockDim.x + threadIdx.x;
    if (idx < DD * DD) {
        int c = idx >> 7, k = idx & 127;
        Wt[idx] = __float2bfloat16(Wm[k * DD + c]);
    }
}

// ---------------- fused bucket gather: LDS CSR build + register accumulate
__global__ __launch_bounds__(512) void bgather_kernel(
        const __hip_bfloat16* __restrict__ hb,
        const unsigned int* __restrict__ eparts,
        const unsigned int* __restrict__ bucket_base,
        __hip_bfloat16* __restrict__ aggb, int num_dst) {
    __shared__ unsigned int lcsr[BKT * MAXDEG];  // 16KB
    __shared__ unsigned int cur[BKT];
    int t = threadIdx.x, wid = t >> 6, lane = t & 63;
    int b = blockIdx.x;
    if (t < BKT) cur[t] = 0;
    __syncthreads();
    unsigned int e0 = bucket_base[b], e1 = bucket_base[b + 1];
    for (unsigned int i = e0 + t; i < e1; i += 512) {
        unsigned int e = eparts[i];
        unsigned int dlow = e >> 24;
        unsigned int pos = atomicAdd(&cur[dlow], 1u);   // LDS int atomic
        if (pos < MAXDEG) lcsr[dlow * MAXDEG + pos] = e & 0xFFFFFFu;
    }
    __syncthreads();
    const __hip_bfloat162* hb2 = reinterpret_cast<const __hip_bfloat162*>(hb);
    for (int r = wid; r < BKT; r += 8) {
        int row = b * BKT + r;
        if (row >= num_dst) break;
        unsigned int degu = cur[r];
        int deg = (int)degu; if (deg > MAXDEG) deg = MAXDEG;
        const int4* crow = reinterpret_cast<const int4*>(&lcsr[r * MAXDEG]);
        float ax = 0.f, ay = 0.f;
        int i = 0;
        for (; i + 8 <= deg; i += 8) {
            int4 q0 = crow[i >> 2];
            int4 q1 = crow[(i >> 2) + 1];
            float2 v0 = __bfloat1622float2(hb2[(size_t)q0.x * 64 + lane]);
            float2 v1 = __bfloat1622float2(hb2[(size_t)q0.y * 64 + lane]);
            float2 v2 = __bfloat1622float2(hb2[(size_t)q0.z * 64 + lane]);
            float2 v3 = __bfloat1622float2(hb2[(size_t)q0.w * 64 + lane]);
            float2 v4 = __bfloat1622float2(hb2[(size_t)q1.x * 64 + lane]);
            float2 v5 = __bfloat1622float2(hb2[(size_t)q1.y * 64 + lane]);
            float2 v6 = __bfloat1622float2(hb2[(size_t)q1.z * 64 + lane]);
            float2 v7 = __bfloat1622float2(hb2[(size_t)q1.w * 64 + lane]);
            ax += v0.x + v1.x + v2.x + v3.x + v4.x + v5.x + v6.x + v7.x;
            ay += v0.y + v1.y + v2.y + v3.y + v4.y + v5.y + v6.y + v7.y;
        }
        for (; i < deg; ++i) {
            unsigned int s = lcsr[r * MAXDEG + i];
            float2 vv = __bfloat1622float2(hb2[(size_t)s * 64 + lane]);
            ax += vv.x; ay += vv.y;
        }
        float scd = rsqrtf(fmaxf((float)degu, 1.0f));
        *reinterpret_cast<__hip_bfloat162*>(aggb + (size_t)row * DD + lane * 2) =
            __float22bfloat162_rn(make_float2(ax * scd, ay * scd));
    }
}

// ---------------- fallback: R7 path kernels
__global__ void fillc_kernel(const int* __restrict__ src, const int* __restrict__ dst,
                             unsigned int* __restrict__ cursor,
                             int* __restrict__ csr, int E) {
    int i = blockIdx.x * blockDim.x + threadIdx.x;
    if (i < E) {
        int s = src[i];
        int d = dst[i];
        unsigned int pos = atomicAdd(&cursor[d], 1u);
        if (pos < MAXDEG) csr[(size_t)d * MAXDEG + pos] = s;
    }
}

__global__ __launch_bounds__(256) void gather_kernel(
        const __hip_bfloat16* __restrict__ hb,
        const int* __restrict__ csr, const unsigned int* __restrict__ cursor,
        __hip_bfloat16* __restrict__ aggb, int num_dst) {
    int wave = threadIdx.x >> 6;
    int lane = threadIdx.x & 63;
    int row = blockIdx.x * 4 + wave;
    if (row >= num_dst) return;
    unsigned int degu = cursor[row];
    int deg = (int)degu; if (deg > MAXDEG) deg = MAXDEG;
    const int* crow = csr + (size_t)row * MAXDEG;
    int c = lane * 2;
    float ax = 0.f, ay = 0.f;
    int i = 0;
    for (; i + 4 <= deg; i += 4) {
        int4 s0 = *reinterpret_cast<const int4*>(crow + i);
        float2 v0 = __bfloat1622float2(*reinterpret_cast<const __hip_bfloat162*>(hb + (size_t)s0.x * DD + c));
        float2 v1 = __bfloat1622float2(*reinterpret_cast<const __hip_bfloat162*>(hb + (size_t)s0.y * DD + c));
        float2 v2 = __bfloat1622float2(*reinterpret_cast<const __hip_bfloat162*>(hb + (size_t)s0.z * DD + c));
        float2 v3 = __bfloat1622float2(*reinterpret_cast<const __hip_bfloat162*>(hb + (size_t)s0.w * DD + c));
        ax += v0.x + v1.x + v2.x + v3.x;
        ay += v0.y + v1.y + v2.y + v3.y;
    }
    for (; i < deg; ++i) {
        int s = crow[i];
        float2 vv = __bfloat1622float2(*reinterpret_cast<const __hip_bfloat162*>(hb + (size_t)s * DD + c));
        ax += vv.x; ay += vv.y;
    }
    float scd = rsqrtf(fmaxf((float)degu, 1.0f));
    *reinterpret_cast<__hip_bfloat162*>(aggb + (size_t)row * DD + c) =
        __float22bfloat162_rn(make_float2(ax * scd, ay * scd));
}

// ---------------------- MFMA GEMM (aggb @ W + b) + attention epilogue
__global__ __launch_bounds__(256) void out_mfma_kernel(
        const __hip_bfloat16* __restrict__ aggb,
        const __hip_bfloat16* __restrict__ Wt,
        const float* __restrict__ bias, const float* __restrict__ w_attn,
        float* __restrict__ out, float* __restrict__ alpha_out, int num_dst) {
    int wave = threadIdx.x >> 6;
    int lane = threadIdx.x & 63;
    int row0 = blockIdx.x * 64 + wave * 16;
    if (row0 >= num_dst) return;

    int col = lane & 15;
    int hi  = lane >> 4;

    int arow = row0 + col;
    if (arow >= num_dst) arow = num_dst - 1;

    f32x4 acc[8];
#pragma unroll
    for (int ct = 0; ct < 8; ++ct) acc[ct] = (f32x4)0.f;

    const bf16x8* A = reinterpret_cast<const bf16x8*>(aggb + (size_t)arow * DD);
#pragma unroll
    for (int kg = 0; kg < 4; ++kg) {
        bf16x8 a = A[kg * 4 + hi];
#pragma unroll
        for (int ct = 0; ct < 8; ++ct) {
            const bf16x8* B =
                reinterpret_cast<const bf16x8*>(Wt + (size_t)(ct * 16 + col) * DD);
            bf16x8 b = B[kg * 4 + hi];
            acc[ct] = __builtin_amdgcn_mfma_f32_16x16x32_bf16(a, b, acc[ct], 0, 0, 0);
        }
    }

    float wv[8], bv[8];
#pragma unroll
    for (int ct = 0; ct < 8; ++ct) {
        wv[ct] = w_attn[ct * 16 + col];
        bv[ct] = bias[ct * 16 + col];
    }

#pragma unroll
    for (int r = 0; r < 4; ++r) {
        int row = row0 + hi * 4 + r;
        float v[8];
        float s = 0.f;
#pragma unroll
        for (int ct = 0; ct < 8; ++ct) {
            v[ct] = acc[ct][r] + bv[ct];
            s = fmaf(v[ct], wv[ct], s);
        }
        s += __shfl_xor(s, 1);
        s += __shfl_xor(s, 2);
        s += __shfl_xor(s, 4);
        s += __shfl_xor(s, 8);
        float alpha = 1.0f / (1.0f + expf(-s));
        if (row < num_dst) {
#pragma unroll
            for (int ct = 0; ct < 8; ++ct)
                out[(size_t)row * DD + ct * 16 + col] = v[ct] * alpha;
            if (col == 0) alpha_out[row] = alpha;
        }
    }
}

// ----------------------------------------------------------------- launch
extern "C" void kernel_launch(void* const* d_in, const int* in_sizes, int n_in,
                              void* d_out, int out_size, void* d_ws, size_t ws_size,
                              hipStream_t stream) {
    const float* h      = (const float*)d_in[0];
    const int*   src    = (const int*)d_in[1];
    const int*   dst    = (const int*)d_in[2];
    const float* Wm     = (const float*)d_in[3];
    const float* bias   = (const float*)d_in[4];
    const float* w_attn = (const float*)d_in[5];

    int num_src = in_sizes[0] / DD;
    int E       = in_sizes[1];
    int num_dst = out_size / (DD + 1);
    int NB      = (num_dst + BKT - 1) / BKT;
    int NPASS   = (num_src + HBINS - 1) / HBINS;

    float* out       = (float*)d_out;
    float* alpha_out = out + (size_t)num_dst * DD;

    char* p = (char*)d_ws;
    auto take = [&p](size_t bytes) {
        char* q = p;
        p += (bytes + 255) & ~(size_t)255;
        return q;
    };
    unsigned int* deg_src = (unsigned int*)take((size_t)num_src * 4);
    unsigned int* cursor  = (unsigned int*)take((size_t)num_dst * 4);
    int*          csr     = (int*)take((size_t)num_dst * MAXDEG * 4);
    __hip_bfloat16* aggb  = (__hip_bfloat16*)take((size_t)num_dst * DD * 2);
    __hip_bfloat16* Wt    = (__hip_bfloat16*)take((size_t)DD * DD * 2);
    __hip_bfloat16* hb    = (__hip_bfloat16*)take((size_t)num_src * DD * 2);
    unsigned int* parts   = (unsigned int*)take(((size_t)NPASS * HBLK) << 16);
    size_t full_need = (size_t)(p - (char*)d_ws);

    // bucket path arrays alias the (unused in that path) csr region
    unsigned int* eparts      = (unsigned int*)csr;            // E u32
    unsigned int* bucket_cnt  = eparts + ((E + 7) & ~7);       // NB
    unsigned int* bucket_base = bucket_cnt + NB + 8;           // NB+1
    unsigned int* bucket_cur  = bucket_base + NB + 8;          // NB

    bool use_mp = ws_size >= full_need;
    bool bucket_ok = use_mp && NB <= NB_MAX && num_dst <= 65536 &&
                     num_src < (1 << 24) &&
                     ((size_t)E + 3 * NB + 32) * 4 <= (size_t)num_dst * MAXDEG * 4;

    int thr = 256;
    int pgrid = (E + P_CH - 1) / P_CH;

    if (bucket_ok) {
        hipMemsetAsync(bucket_cnt, 0, (size_t)NB * 4, stream);
        hist_part_kernel<<<NPASS * HBLK, HTHR, 0, stream>>>(src, parts, E);
        hist_merge_kernel<<<(num_src + thr - 1) / thr, thr, 0, stream>>>(
            parts, deg_src, num_src);
        pcount_kernel<<<pgrid, 1024, 0, stream>>>(dst, bucket_cnt, E, NB);
        pscan_kernel<<<1, 64, 0, stream>>>(bucket_cnt, bucket_base, bucket_cur, NB);
        pscatter_kernel<<<pgrid, 1024, 0, stream>>>(src, dst, bucket_cur, eparts,
                                                    E, NB);
        int totalc = num_src * (DD / 8);
        conv_kernel<<<(totalc + thr - 1) / thr, thr, 0, stream>>>(h, deg_src, hb,
                                                                  num_src);
        wt_kernel<<<(DD * DD + thr - 1) / thr, thr, 0, stream>>>(Wm, Wt);
        bgather_kernel<<<NB, 512, 0, stream>>>(hb, eparts, bucket_base, aggb,
                                               num_dst);
    } else if (use_mp) {
        hipMemsetAsync(cursor, 0, (size_t)num_dst * 4, stream);
        hist_part_kernel<<<NPASS * HBLK, HTHR, 0, stream>>>(src, parts, E);
        hist_merge_kernel<<<(num_src + thr - 1) / thr, thr, 0, stream>>>(
            parts, deg_src, num_src);
        fillc_kernel<<<(E + thr - 1) / thr, thr, 0, stream>>>(src, dst, cursor,
                                                              csr, E);
        int totalc = num_src * (DD / 8);
        conv_kernel<<<(totalc + thr - 1) / thr, thr, 0, stream>>>(h, deg_src, hb,
                                                                  num_src);
        wt_kernel<<<(DD * DD + thr - 1) / thr, thr, 0, stream>>>(Wm, Wt);
        int grid_g = (num_dst + 3) / 4;
        gather_kernel<<<grid_g, thr, 0, stream>>>(hb, csr, cursor, aggb, num_dst);
    } else {
        // minimal-ws fallback: single fused atomic fill + gather (R5 semantics)
        hipMemsetAsync(deg_src, 0, (size_t)num_src * 4, stream);
        hipMemsetAsync(cursor, 0, (size_t)num_dst * 4, stream);
        fillc_kernel<<<(E + thr - 1) / thr, thr, 0, stream>>>(src, dst, cursor,
                                                              csr, E);
        // build deg_src with global atomics folded into conv path is not
        // possible; reuse hist via parts if it fits, else atomic histogram:
        // (ws too small for parts -> use atomic histogram on deg_src)
        // simple atomic histogram:
        // note: rare path; correctness over speed
        struct L { static __global__ void k(const int* s, unsigned int* d, int n) {
        } };
        // fallthrough: use fillc's cursor for deg_dst, atomic deg_src:
        // launch a tiny lambda-free kernel: reuse hist_merge? Not applicable.
        // Use conv with deg computed from atomic histogram:
        // (we accept the extra pass)
        // atomic histogram kernel defined below via hist_atomic
        extern __global__ void hist_atomic_kernel(const int*, unsigned int*, int);
        hipLaunchKernelGGL(hist_atomic_kernel, dim3((E + thr - 1) / thr), dim3(thr),
                           0, stream, src, deg_src, E);
        int totalc = num_src * (DD / 8);
        conv_kernel<<<(totalc + thr - 1) / thr, thr, 0, stream>>>(h, deg_src, hb,
                                                                  num_src);
        wt_kernel<<<(DD * DD + thr - 1) / thr, thr, 0, stream>>>(Wm, Wt);
        int grid_g = (num_dst + 3) / 4;
        gather_kernel<<<grid_g, thr, 0, stream>>>(hb, csr, cursor, aggb, num_dst);
    }

    int grid_c = (num_dst + 63) / 64;
    out_mfma_kernel<<<grid_c, thr, 0, stream>>>(aggb, Wt, bias, w_attn,
                                                out, alpha_out, num_dst);
}

// atomic histogram for the minimal-ws fallback path
__global__ void hist_atomic_kernel(const int* __restrict__ src,
                                   unsigned int* __restrict__ deg_src, int E) {
    int i = blockIdx.x * blockDim.x + threadIdx.x;
    if (i < E) atomicAdd(&deg_src[src[i]], 1u);
}

// Round 9
// 116.099 us; speedup vs baseline: 6.8095x; 1.0514x over previous
//
#include <hip/hip_runtime.h>
#include <hip/hip_bf16.h>
#include <math.h>

#define DD 128
#define MAXDEG 64
#define BKT 64               // dst rows per bucket
#define NB_MAX 1024
#define P_CH 8192            // edges per partition block
#define HBINS 16384          // bins per deg_src histogram pass (64KB LDS)
#define HBLK  32
#define HTHR  1024

using bf16x8 = __attribute__((ext_vector_type(8))) short;
using f32x4  = __attribute__((ext_vector_type(4))) float;

struct alignas(16) bfq { __hip_bfloat162 q[4]; };

// =============== K1: deg_src multipass hist (role A) + bucket count (role B)
__global__ __launch_bounds__(1024) void k1_kernel(
        const int* __restrict__ src, const int* __restrict__ dst,
        unsigned int* __restrict__ parts, unsigned int* __restrict__ bucket_cnt,
        int E, int NB, int nHist) {
    __shared__ unsigned int smem[HBINS];   // 64KB
    int t = threadIdx.x;
    int bid = blockIdx.x;
    if (bid < nHist) {
        int pass = bid / HBLK;
        int blk  = bid % HBLK;
        int lo   = pass * HBINS;
        for (int i = t; i < HBINS; i += 1024) smem[i] = 0;
        __syncthreads();
        int chunk = (E + HBLK - 1) / HBLK;
        int c0 = blk * chunk;
        int c1 = c0 + chunk; if (c1 > E) c1 = E;
        for (int i = c0 + t; i < c1; i += 1024) {
            unsigned int u = (unsigned int)(src[i] - lo);
            if (u < HBINS) atomicAdd(&smem[u], 1u);
        }
        __syncthreads();
        unsigned int* dstp = parts + ((size_t)bid << 14);
        for (int i = t; i < HBINS; i += 1024) dstp[i] = smem[i];
    } else {
        int b2 = bid - nHist;
        for (int b = t; b < NB; b += 1024) smem[b] = 0;
        __syncthreads();
        int c0 = b2 * P_CH;
        int c1 = c0 + P_CH; if (c1 > E) c1 = E;
        for (int i = c0 + t; i < c1; i += 1024)
            atomicAdd(&smem[dst[i] >> 6], 1u);
        __syncthreads();
        for (int b = t; b < NB; b += 1024)
            if (smem[b]) atomicAdd(&bucket_cnt[b], smem[b]);
    }
}

// =============== K2: hist merge (role A) + bucket exclusive scan (role B)
__global__ __launch_bounds__(256) void k2_kernel(
        const unsigned int* __restrict__ parts, unsigned int* __restrict__ deg_src,
        int num_src, const unsigned int* __restrict__ bucket_cnt,
        unsigned int* __restrict__ bucket_base, unsigned int* __restrict__ bucket_cur,
        int NB, int nMerge) {
    int bid = blockIdx.x;
    if (bid < nMerge) {
        int g = bid * 256 + threadIdx.x;
        if (g >= num_src) return;
        int pass = g >> 14;
        int r = g & (HBINS - 1);
        const unsigned int* p = parts + ((size_t)(pass * HBLK) << 14) + r;
        unsigned int s = 0;
#pragma unroll
        for (int b = 0; b < HBLK; ++b) s += p[(size_t)b << 14];
        deg_src[g] = s;
    } else {
        int lane = threadIdx.x;
        if (lane >= 64) return;
        unsigned int carry = 0;
        for (int b0 = 0; b0 < NB; b0 += 64) {
            int i = b0 + lane;
            unsigned int v = (i < NB) ? bucket_cnt[i] : 0u;
            unsigned int incl = v;
#pragma unroll
            for (int off = 1; off < 64; off <<= 1) {
                unsigned int u = __shfl_up(incl, off);
                if (lane >= off) incl += u;
            }
            unsigned int excl = incl - v + carry;
            if (i < NB) { bucket_base[i] = excl; bucket_cur[i] = excl; }
            carry += __shfl(incl, 63);
        }
        if (lane == 0) bucket_base[NB] = carry;
    }
}

// =============== K3: conv h->hb (role A) + W transpose (role B) + pscatter (C)
__global__ __launch_bounds__(1024) void k3_kernel(
        const float* __restrict__ h, const unsigned int* __restrict__ deg_src,
        __hip_bfloat16* __restrict__ hb, const float* __restrict__ Wm,
        __hip_bfloat16* __restrict__ Wt, const int* __restrict__ src,
        const int* __restrict__ dst, unsigned int* __restrict__ bucket_cur,
        unsigned int* __restrict__ eparts, int E, int NB, int num_src,
        int nConv, int nWt) {
    __shared__ unsigned int smem[15360];   // 60KB (pscatter role)
    int t = threadIdx.x;
    int bid = blockIdx.x;
    if (bid < nConv) {
        int idx = bid * 1024 + t;          // one thread per 8 elems
        int total = num_src * (DD / 8);
        if (idx >= total) return;
        int row = idx >> 4;
        int c0  = (idx & 15) * 8;
        float nrm = rsqrtf(fmaxf((float)deg_src[row], 1.0f));
        const float4* p = reinterpret_cast<const float4*>(h + (size_t)row * DD + c0);
        float4 a = p[0], b = p[1];
        bfq o;
        o.q[0] = __float22bfloat162_rn(make_float2(a.x * nrm, a.y * nrm));
        o.q[1] = __float22bfloat162_rn(make_float2(a.z * nrm, a.w * nrm));
        o.q[2] = __float22bfloat162_rn(make_float2(b.x * nrm, b.y * nrm));
        o.q[3] = __float22bfloat162_rn(make_float2(b.z * nrm, b.w * nrm));
        *reinterpret_cast<bfq*>(hb + (size_t)row * DD + c0) = o;
    } else if (bid < nConv + nWt) {
        int idx = (bid - nConv) * 1024 + t;
        if (idx < DD * DD) {
            int c = idx >> 7, k = idx & 127;
            Wt[idx] = __float2bfloat16(Wm[k * DD + c]);
        }
    } else {
        int b2 = bid - nConv - nWt;
        unsigned int*   stage_s = smem;                             // 8192 u32
        unsigned short* stage_d = (unsigned short*)(smem + 8192);   // 8192 u16
        unsigned int*   lhist   = smem + 12288;                     // 1024
        unsigned int*   lbase   = smem + 13312;                     // 1024
        unsigned int*   gbase   = smem + 14336;                     // 1024
        for (int b = t; b < NB_MAX; b += 1024) lhist[b] = 0;
        __syncthreads();
        int c0 = b2 * P_CH;
        int cnt = E - c0; if (cnt > P_CH) cnt = P_CH;
        int dreg[8], sreg[8];
#pragma unroll
        for (int k = 0; k < 8; ++k) {
            int j = t + k * 1024;
            if (j < cnt) {
                dreg[k] = dst[c0 + j];
                sreg[k] = src[c0 + j];
                atomicAdd(&lhist[dreg[k] >> 6], 1u);
            }
        }
        __syncthreads();
        // wave-shuffle exclusive scan of lhist[0..1023] (2 barriers)
        int wid = t >> 6, lane = t & 63;
        unsigned int v = lhist[t];
        unsigned int x = v;
#pragma unroll
        for (int off = 1; off < 64; off <<= 1) {
            unsigned int u = __shfl_up(x, off);
            if (lane >= off) x += u;
        }
        if (lane == 63) gbase[wid] = x;    // wave sums (gbase[0..15] scratch)
        __syncthreads();
        if (t < 16) {
            unsigned int w = gbase[t];
            unsigned int y = w;
#pragma unroll
            for (int off = 1; off < 16; off <<= 1) {
                unsigned int u = __shfl_up(y, off);
                if (t >= off) y += u;
            }
            gbase[t] = y - w;              // exclusive wave offset
        }
        __syncthreads();
        unsigned int excl = x - v + gbase[wid];
        __syncthreads();                    // gbase reads done before overwrite
        lbase[t] = excl;
        if (t < NB) {
            unsigned int c = lhist[t];
            gbase[t] = c ? atomicAdd(&bucket_cur[t], c) : 0u;
            lhist[t] = 0u;                 // reuse as local cursor
        }
        __syncthreads();
#pragma unroll
        for (int k = 0; k < 8; ++k) {
            int j = t + k * 1024;
            if (j < cnt) {
                int bin = dreg[k] >> 6;
                unsigned int pos = lbase[bin] + atomicAdd(&lhist[bin], 1u);
                stage_d[pos] = (unsigned short)dreg[k];
                stage_s[pos] = (unsigned int)sreg[k];
            }
        }
        __syncthreads();
        for (int idx = t; idx < cnt; idx += 1024) {
            unsigned int d = stage_d[idx];
            unsigned int bin = d >> 6;
            unsigned int pos = gbase[bin] + ((unsigned int)idx - lbase[bin]);
            eparts[pos] = ((d & 63u) << 24) | stage_s[idx];
        }
    }
}

// =============== K4: fused bucket gather + MFMA GEMM + attention epilogue
__global__ __launch_bounds__(512) void bgather_mfma_kernel(
        const __hip_bfloat16* __restrict__ hb,
        const unsigned int* __restrict__ eparts,
        const unsigned int* __restrict__ bucket_base,
        const __hip_bfloat16* __restrict__ Wt,
        const float* __restrict__ bias, const float* __restrict__ w_attn,
        float* __restrict__ out, float* __restrict__ alpha_out, int num_dst) {
    __shared__ unsigned int lcsr[BKT * MAXDEG];   // 16KB
    __shared__ unsigned int cur[BKT];
    __shared__ __hip_bfloat16 sagg[BKT * DD];     // 16KB, XOR-swizzled
    int t = threadIdx.x, wid = t >> 6, lane = t & 63;
    int b = blockIdx.x;
    if (t < BKT) cur[t] = 0;
    __syncthreads();
    unsigned int e0 = bucket_base[b], e1 = bucket_base[b + 1];
    for (unsigned int i = e0 + t; i < e1; i += 512) {
        unsigned int e = eparts[i];
        unsigned int dlow = e >> 24;
        unsigned int pos = atomicAdd(&cur[dlow], 1u);   // LDS int atomic
        if (pos < MAXDEG) lcsr[dlow * MAXDEG + pos] = e & 0xFFFFFFu;
    }
    __syncthreads();
    const __hip_bfloat162* hb2 = reinterpret_cast<const __hip_bfloat162*>(hb);
    char* sb = (char*)sagg;
    for (int r = wid; r < BKT; r += 8) {
        unsigned int degu = cur[r];
        int deg = (int)degu; if (deg > MAXDEG) deg = MAXDEG;
        const int4* crow = reinterpret_cast<const int4*>(&lcsr[r * MAXDEG]);
        float ax = 0.f, ay = 0.f;
        int i = 0;
        for (; i + 8 <= deg; i += 8) {
            int4 q0 = crow[i >> 2];
            int4 q1 = crow[(i >> 2) + 1];
            float2 v0 = __bfloat1622float2(hb2[(size_t)q0.x * 64 + lane]);
            float2 v1 = __bfloat1622float2(hb2[(size_t)q0.y * 64 + lane]);
            float2 v2 = __bfloat1622float2(hb2[(size_t)q0.z * 64 + lane]);
            float2 v3 = __bfloat1622float2(hb2[(size_t)q0.w * 64 + lane]);
            float2 v4 = __bfloat1622float2(hb2[(size_t)q1.x * 64 + lane]);
            float2 v5 = __bfloat1622float2(hb2[(size_t)q1.y * 64 + lane]);
            float2 v6 = __bfloat1622float2(hb2[(size_t)q1.z * 64 + lane]);
            float2 v7 = __bfloat1622float2(hb2[(size_t)q1.w * 64 + lane]);
            ax += v0.x + v1.x + v2.x + v3.x + v4.x + v5.x + v6.x + v7.x;
            ay += v0.y + v1.y + v2.y + v3.y + v4.y + v5.y + v6.y + v7.y;
        }
        for (; i < deg; ++i) {
            unsigned int s = lcsr[r * MAXDEG + i];
            float2 vv = __bfloat1622float2(hb2[(size_t)s * 64 + lane]);
            ax += vv.x; ay += vv.y;
        }
        float scd = rsqrtf(fmaxf((float)degu, 1.0f));
        int byte = r * 256 + lane * 4;
        *reinterpret_cast<__hip_bfloat162*>(sb + (byte ^ ((r & 7) << 4))) =
            __float22bfloat162_rn(make_float2(ax * scd, ay * scd));
    }
    __syncthreads();
    if (wid < 4) {
        int col = lane & 15, hi = lane >> 4;
        int row0 = b * 64 + wid * 16;
        f32x4 acc[8];
#pragma unroll
        for (int ct = 0; ct < 8; ++ct) acc[ct] = (f32x4)0.f;
#pragma unroll
        for (int kg = 0; kg < 4; ++kg) {
            int arow = wid * 16 + col;
            int byte = arow * 256 + (kg * 32 + hi * 8) * 2;
            bf16x8 a = *reinterpret_cast<const bf16x8*>(
                sb + (byte ^ ((arow & 7) << 4)));
#pragma unroll
            for (int ct = 0; ct < 8; ++ct) {
                const bf16x8* B = reinterpret_cast<const bf16x8*>(
                    Wt + (size_t)(ct * 16 + col) * DD);
                bf16x8 bb = B[kg * 4 + hi];
                acc[ct] = __builtin_amdgcn_mfma_f32_16x16x32_bf16(a, bb, acc[ct],
                                                                  0, 0, 0);
            }
        }
        float wv[8], bv[8];
#pragma unroll
        for (int ct = 0; ct < 8; ++ct) {
            wv[ct] = w_attn[ct * 16 + col];
            bv[ct] = bias[ct * 16 + col];
        }
#pragma unroll
        for (int r = 0; r < 4; ++r) {
            int row = row0 + hi * 4 + r;
            float v[8];
            float s = 0.f;
#pragma unroll
            for (int ct = 0; ct < 8; ++ct) {
                v[ct] = acc[ct][r] + bv[ct];
                s = fmaf(v[ct], wv[ct], s);
            }
            s += __shfl_xor(s, 1);
            s += __shfl_xor(s, 2);
            s += __shfl_xor(s, 4);
            s += __shfl_xor(s, 8);
            float alpha = 1.0f / (1.0f + expf(-s));
            if (row < num_dst) {
#pragma unroll
                for (int ct = 0; ct < 8; ++ct)
                    out[(size_t)row * DD + ct * 16 + col] = v[ct] * alpha;
                if (col == 0) alpha_out[row] = alpha;
            }
        }
    }
}

// =============== fallback-path kernels (non-bucket shapes / small ws)
__global__ void hist_atomic_kernel(const int* __restrict__ src,
                                   unsigned int* __restrict__ deg_src, int E) {
    int i = blockIdx.x * blockDim.x + threadIdx.x;
    if (i < E) atomicAdd(&deg_src[src[i]], 1u);
}

__global__ void fillc_kernel(const int* __restrict__ src, const int* __restrict__ dst,
                             unsigned int* __restrict__ cursor,
                             int* __restrict__ csr, int E) {
    int i = blockIdx.x * blockDim.x + threadIdx.x;
    if (i < E) {
        int s = src[i];
        int d = dst[i];
        unsigned int pos = atomicAdd(&cursor[d], 1u);
        if (pos < MAXDEG) csr[(size_t)d * MAXDEG + pos] = s;
    }
}

__global__ __launch_bounds__(256) void gather_kernel(
        const __hip_bfloat16* __restrict__ hb,
        const int* __restrict__ csr, const unsigned int* __restrict__ cursor,
        __hip_bfloat16* __restrict__ aggb, int num_dst) {
    int wave = threadIdx.x >> 6;
    int lane = threadIdx.x & 63;
    int row = blockIdx.x * 4 + wave;
    if (row >= num_dst) return;
    unsigned int degu = cursor[row];
    int deg = (int)degu; if (deg > MAXDEG) deg = MAXDEG;
    const int* crow = csr + (size_t)row * MAXDEG;
    int c = lane * 2;
    float ax = 0.f, ay = 0.f;
    int i = 0;
    for (; i + 4 <= deg; i += 4) {
        int4 s0 = *reinterpret_cast<const int4*>(crow + i);
        float2 v0 = __bfloat1622float2(*reinterpret_cast<const __hip_bfloat162*>(hb + (size_t)s0.x * DD + c));
        float2 v1 = __bfloat1622float2(*reinterpret_cast<const __hip_bfloat162*>(hb + (size_t)s0.y * DD + c));
        float2 v2 = __bfloat1622float2(*reinterpret_cast<const __hip_bfloat162*>(hb + (size_t)s0.z * DD + c));
        float2 v3 = __bfloat1622float2(*reinterpret_cast<const __hip_bfloat162*>(hb + (size_t)s0.w * DD + c));
        ax += v0.x + v1.x + v2.x + v3.x;
        ay += v0.y + v1.y + v2.y + v3.y;
    }
    for (; i < deg; ++i) {
        int s = crow[i];
        float2 vv = __bfloat1622float2(*reinterpret_cast<const __hip_bfloat162*>(hb + (size_t)s * DD + c));
        ax += vv.x; ay += vv.y;
    }
    float scd = rsqrtf(fmaxf((float)degu, 1.0f));
    *reinterpret_cast<__hip_bfloat162*>(aggb + (size_t)row * DD + c) =
        __float22bfloat162_rn(make_float2(ax * scd, ay * scd));
}

__global__ __launch_bounds__(256) void out_mfma_kernel(
        const __hip_bfloat16* __restrict__ aggb,
        const __hip_bfloat16* __restrict__ Wt,
        const float* __restrict__ bias, const float* __restrict__ w_attn,
        float* __restrict__ out, float* __restrict__ alpha_out, int num_dst) {
    int wave = threadIdx.x >> 6;
    int lane = threadIdx.x & 63;
    int row0 = blockIdx.x * 64 + wave * 16;
    if (row0 >= num_dst) return;
    int col = lane & 15;
    int hi  = lane >> 4;
    int arow = row0 + col;
    if (arow >= num_dst) arow = num_dst - 1;
    f32x4 acc[8];
#pragma unroll
    for (int ct = 0; ct < 8; ++ct) acc[ct] = (f32x4)0.f;
    const bf16x8* A = reinterpret_cast<const bf16x8*>(aggb + (size_t)arow * DD);
#pragma unroll
    for (int kg = 0; kg < 4; ++kg) {
        bf16x8 a = A[kg * 4 + hi];
#pragma unroll
        for (int ct = 0; ct < 8; ++ct) {
            const bf16x8* B =
                reinterpret_cast<const bf16x8*>(Wt + (size_t)(ct * 16 + col) * DD);
            bf16x8 b = B[kg * 4 + hi];
            acc[ct] = __builtin_amdgcn_mfma_f32_16x16x32_bf16(a, b, acc[ct], 0, 0, 0);
        }
    }
    float wv[8], bv[8];
#pragma unroll
    for (int ct = 0; ct < 8; ++ct) {
        wv[ct] = w_attn[ct * 16 + col];
        bv[ct] = bias[ct * 16 + col];
    }
#pragma unroll
    for (int r = 0; r < 4; ++r) {
        int row = row0 + hi * 4 + r;
        float v[8];
        float s = 0.f;
#pragma unroll
        for (int ct = 0; ct < 8; ++ct) {
            v[ct] = acc[ct][r] + bv[ct];
            s = fmaf(v[ct], wv[ct], s);
        }
        s += __shfl_xor(s, 1);
        s += __shfl_xor(s, 2);
        s += __shfl_xor(s, 4);
        s += __shfl_xor(s, 8);
        float alpha = 1.0f / (1.0f + expf(-s));
        if (row < num_dst) {
#pragma unroll
            for (int ct = 0; ct < 8; ++ct)
                out[(size_t)row * DD + ct * 16 + col] = v[ct] * alpha;
            if (col == 0) alpha_out[row] = alpha;
        }
    }
}

// ----------------------------------------------------------------- launch
extern "C" void kernel_launch(void* const* d_in, const int* in_sizes, int n_in,
                              void* d_out, int out_size, void* d_ws, size_t ws_size,
                              hipStream_t stream) {
    const float* h      = (const float*)d_in[0];
    const int*   src    = (const int*)d_in[1];
    const int*   dst    = (const int*)d_in[2];
    const float* Wm     = (const float*)d_in[3];
    const float* bias   = (const float*)d_in[4];
    const float* w_attn = (const float*)d_in[5];

    int num_src = in_sizes[0] / DD;
    int E       = in_sizes[1];
    int num_dst = out_size / (DD + 1);
    int NB      = (num_dst + BKT - 1) / BKT;
    int NPASS   = (num_src + HBINS - 1) / HBINS;

    float* out       = (float*)d_out;
    float* alpha_out = out + (size_t)num_dst * DD;

    char* p = (char*)d_ws;
    auto take = [&p](size_t bytes) {
        char* q = p;
        p += (bytes + 255) & ~(size_t)255;
        return q;
    };
    unsigned int* deg_src = (unsigned int*)take((size_t)num_src * 4);
    unsigned int* cursor  = (unsigned int*)take((size_t)num_dst * 4);
    int*          csr     = (int*)take((size_t)num_dst * MAXDEG * 4);
    __hip_bfloat16* aggb  = (__hip_bfloat16*)take((size_t)num_dst * DD * 2);
    __hip_bfloat16* Wt    = (__hip_bfloat16*)take((size_t)DD * DD * 2);
    __hip_bfloat16* hb    = (__hip_bfloat16*)take((size_t)num_src * DD * 2);
    unsigned int* parts   = (unsigned int*)take(((size_t)NPASS * HBLK) << 16);
    size_t full_need = (size_t)(p - (char*)d_ws);

    // bucket-path arrays alias the (unused in that path) csr region
    unsigned int* eparts      = (unsigned int*)csr;            // E u32
    unsigned int* bucket_cnt  = eparts + ((E + 7) & ~7);       // NB
    unsigned int* bucket_base = bucket_cnt + NB + 8;           // NB+1
    unsigned int* bucket_cur  = bucket_base + NB + 8;          // NB

    bool use_mp = ws_size >= full_need;
    bool bucket_ok = use_mp && NB <= NB_MAX && num_dst <= 65536 &&
                     num_src < (1 << 24) &&
                     ((size_t)E + 3 * NB + 32) * 4 <= (size_t)num_dst * MAXDEG * 4;

    int thr = 256;
    int nHist  = NPASS * HBLK;
    int nPc    = (E + P_CH - 1) / P_CH;
    int nMerge = (num_src + 255) / 256;
    int nConv  = (num_src * (DD / 8) + 1023) / 1024;
    int nWt    = (DD * DD + 1023) / 1024;

    if (bucket_ok) {
        hipMemsetAsync(bucket_cnt, 0, (size_t)NB * 4, stream);
        k1_kernel<<<nHist + nPc, 1024, 0, stream>>>(src, dst, parts, bucket_cnt,
                                                    E, NB, nHist);
        k2_kernel<<<nMerge + 1, 256, 0, stream>>>(parts, deg_src, num_src,
                                                  bucket_cnt, bucket_base,
                                                  bucket_cur, NB, nMerge);
        k3_kernel<<<nConv + nWt + nPc, 1024, 0, stream>>>(
            h, deg_src, hb, Wm, Wt, src, dst, bucket_cur, eparts, E, NB, num_src,
            nConv, nWt);
        bgather_mfma_kernel<<<NB, 512, 0, stream>>>(hb, eparts, bucket_base, Wt,
                                                    bias, w_attn, out, alpha_out,
                                                    num_dst);
    } else if (use_mp) {
        hipMemsetAsync(cursor, 0, (size_t)num_dst * 4, stream);
        k1_kernel<<<nHist, 1024, 0, stream>>>(src, dst, parts, cursor /*unused*/,
                                              E, 0, nHist);
        k2_kernel<<<nMerge, 256, 0, stream>>>(parts, deg_src, num_src, cursor,
                                              cursor, cursor, 0, nMerge);
        fillc_kernel<<<(E + thr - 1) / thr, thr, 0, stream>>>(src, dst, cursor,
                                                              csr, E);
        k3_kernel<<<nConv + nWt, 1024, 0, stream>>>(
            h, deg_src, hb, Wm, Wt, src, dst, cursor, (unsigned int*)csr, E, 0,
            num_src, nConv, nWt);
        int grid_g = (num_dst + 3) / 4;
        gather_kernel<<<grid_g, thr, 0, stream>>>(hb, csr, cursor, aggb, num_dst);
        int grid_c = (num_dst + 63) / 64;
        out_mfma_kernel<<<grid_c, thr, 0, stream>>>(aggb, Wt, bias, w_attn,
                                                    out, alpha_out, num_dst);
    } else {
        hipMemsetAsync(deg_src, 0, (size_t)num_src * 4, stream);
        hipMemsetAsync(cursor, 0, (size_t)num_dst * 4, stream);
        hist_atomic_kernel<<<(E + thr - 1) / thr, thr, 0, stream>>>(src, deg_src, E);
        fillc_kernel<<<(E + thr - 1) / thr, thr, 0, stream>>>(src, dst, cursor,
                                                              csr, E);
        k3_kernel<<<nConv + nWt, 1024, 0, stream>>>(
            h, deg_src, hb, Wm, Wt, src, dst, cursor, (unsigned int*)csr, E, 0,
            num_src, nConv, nWt);
        int grid_g = (num_dst + 3) / 4;
        gather_kernel<<<grid_g, thr, 0, stream>>>(hb, csr, cursor, aggb, num_dst);
        int grid_c = (num_dst + 63) / 64;
        out_mfma_kernel<<<grid_c, thr, 0, stream>>>(aggb, Wt, bias, w_attn,
                                                    out, alpha_out, num_dst);
    }
}